// Round 4
// baseline (556.774 us; speedup 1.0000x reference)
//
#include <hip/hip_runtime.h>

// NeighborlistVerletNsq: all-unique-pairs minimum-image displacement + distance
// + verlet-build / cutoff masks on MI355X.
//
// N = 6144 particles, P = N(N-1)/2 = 18,871,296 pairs.
// Output layout (flat f32, concatenated in reference return order):
//   [0,      3P)  r_ij  (row-major [P,3])
//   [3P,     4P)  d_ij
//   [4P,     5P)  in_build  (1.0f / 0.0f)
//   [5P,     6P)  in_cutoff (1.0f / 0.0f)
//
// V3b: V2 + NONTEMPORAL stores (fixed: __builtin_nontemporal_store needs a
// native clang vector type, not HIP_vector_type<float,4>).
// Theory: kernel time (~142 us) == 2x the 453 MB write roofline (74 us) ==
// read-for-ownership on L2 store misses (453 MB write + 453 MB RFO fetch at
// 6.1 TB/s = 148 us, matching both V1 and V2). Output is write-once and never
// re-read -> no-allocate streaming stores should eliminate the RFO fetch.

#define NPART 6144
#define PAIRS ((NPART * (NPART - 1)) / 2)   // 18,871,296  (fits int32)
#define NQUAD (PAIRS / 4)                   // 4,717,824 threads

typedef float f32x4 __attribute__((ext_vector_type(4)));

// Replicates jnp.remainder(t, L) then -half, bitwise in fp32, for the
// restricted domain t in (-L/2, 3L/2) that holds because positions in [0, L).
__device__ __forceinline__ float min_image(float diff, float L, float half) {
    float t = __fadd_rn(diff, half);
    float m = t;
    if (t >= L)      m = __fsub_rn(t, L);
    else if (t < 0.f) m = __fadd_rn(t, L);
    return __fsub_rn(m, half);
}

__device__ __forceinline__ void nt_store4(float* p, float a, float b, float c, float d) {
    f32x4 v = {a, b, c, d};
    __builtin_nontemporal_store(v, reinterpret_cast<f32x4*>(p));
}

__global__ __launch_bounds__(256) void nsq_pairs4_kernel(
    const float* __restrict__ pos,   // [N,3]
    const float* __restrict__ box,   // [3,3] diagonal
    float* __restrict__ out)
{
    int t = blockIdx.x * blockDim.x + threadIdx.x;
    if (t >= NQUAD) return;
    const int p0 = t << 2;                        // first of 4 pairs

    // ---- invert p0 -> (i, j), i < j, np.triu_indices order (once per 4) ----
    const double A = (double)(2 * NPART - 1);
    double disc = A * A - 8.0 * (double)p0;
    int i = (int)((A - sqrt(disc)) * 0.5);
    i = max(0, min(i, NPART - 2));
    int rs = i * NPART - (i * (i + 1)) / 2;       // row_start(i)
    int rlen = NPART - 1 - i;
    while (p0 >= rs + rlen) { rs += rlen; ++i; rlen = NPART - 1 - i; }
    while (p0 < rs)         { rs -= (NPART - i); --i; rlen = NPART - 1 - i; }
    int j = i + 1 + (p0 - rs);

    // ---- box lengths (uniform) ----
    float Lx = box[0], Ly = box[4], Lz = box[8];
    float hx = __fmul_rn(Lx, 0.5f);
    float hy = __fmul_rn(Ly, 0.5f);
    float hz = __fmul_rn(Lz, 0.5f);

    float xi = pos[3 * i + 0], yi = pos[3 * i + 1], zi = pos[3 * i + 2];

    float rbuf[12], dbuf[4], b1[4], b2[4];

    #pragma unroll
    for (int k = 0; k < 4; ++k) {
        if (k > 0) {
            ++j;
            if (j >= NPART) {                      // rare: row wrap
                ++i; j = i + 1;
                xi = pos[3 * i + 0]; yi = pos[3 * i + 1]; zi = pos[3 * i + 2];
            }
        }
        float xj = pos[3 * j + 0], yj = pos[3 * j + 1], zj = pos[3 * j + 2];

        float rx = min_image(__fsub_rn(xi, xj), Lx, hx);
        float ry = min_image(__fsub_rn(yi, yj), Ly, hy);
        float rz = min_image(__fsub_rn(zi, zj), Lz, hz);

        float s = __fadd_rn(__fadd_rn(__fmul_rn(rx, rx), __fmul_rn(ry, ry)),
                            __fmul_rn(rz, rz));
        float d = sqrtf(s);

        rbuf[3 * k + 0] = rx;
        rbuf[3 * k + 1] = ry;
        rbuf[3 * k + 2] = rz;
        dbuf[k] = d;
        b1[k] = (d <  0.6f) ? 1.0f : 0.0f;         // CUTOFF + SKIN
        b2[k] = (d <= 0.5f) ? 1.0f : 0.0f;         // CUTOFF
    }

    // ---- nontemporal vectorized stores: 6x dwordx4 nt, all 16B-aligned ----
    const int P = PAIRS;
    float* rq = out + (size_t)12 * t;
    nt_store4(rq + 0, rbuf[0], rbuf[1], rbuf[2],  rbuf[3]);
    nt_store4(rq + 4, rbuf[4], rbuf[5], rbuf[6],  rbuf[7]);
    nt_store4(rq + 8, rbuf[8], rbuf[9], rbuf[10], rbuf[11]);

    nt_store4(out + (size_t)3 * P + 4 * (size_t)t, dbuf[0], dbuf[1], dbuf[2], dbuf[3]);
    nt_store4(out + (size_t)4 * P + 4 * (size_t)t, b1[0], b1[1], b1[2], b1[3]);
    nt_store4(out + (size_t)5 * P + 4 * (size_t)t, b2[0], b2[1], b2[2], b2[3]);
}

extern "C" void kernel_launch(void* const* d_in, const int* in_sizes, int n_in,
                              void* d_out, int out_size, void* d_ws, size_t ws_size,
                              hipStream_t stream) {
    const float* pos = (const float*)d_in[0];   // [6144, 3] f32
    const float* box = (const float*)d_in[1];   // [3, 3]  f32
    float* out = (float*)d_out;                 // 6P f32

    const int block = 256;
    const int grid = (NQUAD + block - 1) / block;  // 18,429 blocks
    nsq_pairs4_kernel<<<grid, block, 0, stream>>>(pos, box, out);
}

// Round 5
// 442.712 us; speedup vs baseline: 1.2576x; 1.2576x over previous
//
#include <hip/hip_runtime.h>

// NeighborlistVerletNsq — V4: LDS-staged block-contiguous r_ij stores.
//
// N = 6144, P = N(N-1)/2 = 18,871,296 pairs. Output (flat f32):
//   [0,3P) r_ij [P,3] | [3P,4P) d_ij | [4P,5P) in_build | [5P,6P) in_cutoff
//
// Findings so far:
//  V2 (4 pairs/thread, dwordx4 stores): kernel ~142 us = 3.2 TB/s vs the
//    harness fill's 6.25 TB/s on the same buffer. V1==V2 -> not VALU-bound.
//  V3b (nontemporal): kernel ~270 us -> nt bypasses L2 write-combining; the
//    cached path was load-bearing. REVERTED.
// Remaining structural difference vs the 6.25 TB/s fill: the r_ij region
// (half of all bytes) is written as 16B chunks at 48B lane stride -> every
// store instruction touches 64 lines partially. Fix: stage r via LDS, store
// block-contiguous (1KB/wave/inst, fill-like). d/b1/b2 already contiguous.

#define NPART 6144
#define PAIRS ((NPART * (NPART - 1)) / 2)   // 18,871,296
#define NQUAD (PAIRS / 4)                   // 4,717,824 threads, 18,429 blocks (exact)

typedef float f32x4 __attribute__((ext_vector_type(4)));

// Replicates jnp.remainder(t, L) then -half, bitwise in fp32, for the
// restricted domain t in (-L/2, 3L/2) that holds because positions in [0, L).
__device__ __forceinline__ float min_image(float diff, float L, float half) {
    float t = __fadd_rn(diff, half);
    float m = t;
    if (t >= L)      m = __fsub_rn(t, L);
    else if (t < 0.f) m = __fadd_rn(t, L);
    return __fsub_rn(m, half);
}

__global__ __launch_bounds__(256) void nsq_pairs4_lds_kernel(
    const float* __restrict__ pos,   // [N,3]
    const float* __restrict__ box,   // [3,3] diagonal
    float* __restrict__ out)
{
    __shared__ float lds_r[3072];               // 12 KB: this block's r_ij

    const int tid = threadIdx.x;
    const int t = blockIdx.x * 256 + tid;       // grid is exact: t < NQUAD always
    const int p0 = t << 2;                      // first of 4 pairs

    // ---- invert p0 -> (i, j): int32 disc (exact), f32 sqrt, loop fixups ----
    const int Ai = 2 * NPART - 1;               // 12287
    int disc = Ai * Ai - 8 * p0;                // max 150,970,369: fits int32
    float sq = sqrtf((float)disc);
    int i = (int)(((float)Ai - sq) * 0.5f);
    i = max(0, min(i, NPART - 2));
    int rs = i * NPART - (i * (i + 1)) / 2;     // row_start(i)
    int rlen = NPART - 1 - i;
    while (p0 >= rs + rlen) { rs += rlen; ++i; rlen = NPART - 1 - i; }
    while (p0 < rs)         { rs -= (NPART - i); --i; rlen = NPART - 1 - i; }
    int j = i + 1 + (p0 - rs);

    // ---- box lengths (uniform) ----
    float Lx = box[0], Ly = box[4], Lz = box[8];
    float hx = __fmul_rn(Lx, 0.5f);
    float hy = __fmul_rn(Ly, 0.5f);
    float hz = __fmul_rn(Lz, 0.5f);

    float xi = pos[3 * i + 0], yi = pos[3 * i + 1], zi = pos[3 * i + 2];

    float rbuf[12], dbuf[4], b1[4], b2[4];

    #pragma unroll
    for (int k = 0; k < 4; ++k) {
        if (k > 0) {
            ++j;
            if (j >= NPART) {                   // rare: row wrap
                ++i; j = i + 1;
                xi = pos[3 * i + 0]; yi = pos[3 * i + 1]; zi = pos[3 * i + 2];
            }
        }
        float xj = pos[3 * j + 0], yj = pos[3 * j + 1], zj = pos[3 * j + 2];

        float rx = min_image(__fsub_rn(xi, xj), Lx, hx);
        float ry = min_image(__fsub_rn(yi, yj), Ly, hy);
        float rz = min_image(__fsub_rn(zi, zj), Lz, hz);

        float s = __fadd_rn(__fadd_rn(__fmul_rn(rx, rx), __fmul_rn(ry, ry)),
                            __fmul_rn(rz, rz));
        float d = sqrtf(s);

        rbuf[3 * k + 0] = rx;
        rbuf[3 * k + 1] = ry;
        rbuf[3 * k + 2] = rz;
        dbuf[k] = d;
        b1[k] = (d <  0.6f) ? 1.0f : 0.0f;      // CUTOFF + SKIN
        b2[k] = (d <= 0.5f) ? 1.0f : 0.0f;      // CUTOFF
    }

    // ---- d/b1/b2: already lane-contiguous float4 -> store direct ----
    const int P = PAIRS;
    *reinterpret_cast<f32x4*>(out + (size_t)3 * P + 4 * (size_t)t) =
        (f32x4){dbuf[0], dbuf[1], dbuf[2], dbuf[3]};
    *reinterpret_cast<f32x4*>(out + (size_t)4 * P + 4 * (size_t)t) =
        (f32x4){b1[0], b1[1], b1[2], b1[3]};
    *reinterpret_cast<f32x4*>(out + (size_t)5 * P + 4 * (size_t)t) =
        (f32x4){b2[0], b2[1], b2[2], b2[3]};

    // ---- r_ij: stage in LDS, then block-contiguous coalesced stores ----
    // LDS write: 48B/thread at 48B stride -> 2-way bank aliasing (free).
    f32x4* lv = reinterpret_cast<f32x4*>(&lds_r[12 * tid]);
    lv[0] = (f32x4){rbuf[0], rbuf[1], rbuf[2],  rbuf[3]};
    lv[1] = (f32x4){rbuf[4], rbuf[5], rbuf[6],  rbuf[7]};
    lv[2] = (f32x4){rbuf[8], rbuf[9], rbuf[10], rbuf[11]};
    __syncthreads();

    // Block's r chunk: 3072 floats at out + 3072*blockIdx.x. 768 float4s,
    // 3 per thread; each wave stores 1KB contiguous per instruction.
    float* rbase = out + (size_t)3072 * blockIdx.x;
    #pragma unroll
    for (int m = 0; m < 3; ++m) {
        int idx = m * 256 + tid;
        f32x4 v = *reinterpret_cast<f32x4*>(&lds_r[4 * idx]);
        *reinterpret_cast<f32x4*>(rbase + 4 * (size_t)idx) = v;
    }
}

extern "C" void kernel_launch(void* const* d_in, const int* in_sizes, int n_in,
                              void* d_out, int out_size, void* d_ws, size_t ws_size,
                              hipStream_t stream) {
    const float* pos = (const float*)d_in[0];   // [6144, 3] f32
    const float* box = (const float*)d_in[1];   // [3, 3]  f32
    float* out = (float*)d_out;                 // 6P f32

    const int block = 256;
    const int grid = NQUAD / block;             // 18,429 blocks (exact)
    nsq_pairs4_lds_kernel<<<grid, block, 0, stream>>>(pos, box, out);
}